// Round 3
// baseline (135.135 us; speedup 1.0000x reference)
//
#include <hip/hip_runtime.h>
#include <math.h>

#define NUM_ENT 14541
#define NUM_REL2 474
#define EMBED_D 200
#define BATCH 256
#define GAMMA 9.0f

#define TILE_B 64
#define TILE_N 128
#define CHUNK 40       // D-chunk per LDS stage (5 chunks of 200)
#define STRIDE 44      // 44 mod 32 = 12 -> max 2-way bank alias (free per m136)
#define NQ (CHUNK / 4) // 10 d-quads per chunk

// 256 threads: tx = tid&15 (n), ty = tid>>4 (b). micro-tile 4(b) x 8(n).
__global__ __launch_bounds__(256, 2)
void transe_score_kernel(const float* __restrict__ ent,
                         const float* __restrict__ relE,
                         const int*   __restrict__ sub_idx,
                         const int*   __restrict__ rel_idx,
                         float*       __restrict__ out)
{
    __shared__ float obj_s[TILE_B][STRIDE];   // 11264 B
    __shared__ float ent_s[TILE_N][STRIDE];   // 22528 B
    __shared__ int   s_sub[TILE_B];
    __shared__ int   s_rel[TILE_B];

    const int tid   = threadIdx.x;
    const int nbase = blockIdx.x * TILE_N;
    const int bbase = blockIdx.y * TILE_B;

    if (tid < TILE_B)          s_sub[tid]          = sub_idx[bbase + tid];
    else if (tid < 2 * TILE_B) s_rel[tid - TILE_B] = rel_idx[bbase + tid - TILE_B];
    __syncthreads();

    const int tx = tid & 15;
    const int ty = tid >> 4;

    float acc[4][8];
#pragma unroll
    for (int i = 0; i < 4; ++i)
#pragma unroll
        for (int j = 0; j < 8; ++j) acc[i][j] = 0.0f;

#pragma unroll 1
    for (int c = 0; c < EMBED_D / CHUNK; ++c) {
        const int dbase = c * CHUNK;

        // stage ent tile chunk: 128 rows x 10 float4 = 1280 items
#pragma unroll
        for (int g = 0; g < 5; ++g) {
            const int it  = g * 256 + tid;
            const int row = it / NQ;
            const int col = (it - row * NQ) * 4;
            int eg = nbase + row;
            if (eg >= NUM_ENT) eg = NUM_ENT - 1;   // clamp; stores guarded in epilogue
            *(float4*)&ent_s[row][col] =
                *(const float4*)(ent + (size_t)eg * EMBED_D + dbase + col);
        }
        // stage obj tile chunk: 64 rows x 10 float4 = 640 items
        for (int it = tid; it < TILE_B * NQ; it += 256) {
            const int row = it / NQ;
            const int col = (it - row * NQ) * 4;
            const float4 av = *(const float4*)(ent  + (size_t)s_sub[row] * EMBED_D + dbase + col);
            const float4 rv = *(const float4*)(relE + (size_t)s_rel[row] * EMBED_D + dbase + col);
            float4 ov;
            ov.x = av.x + rv.x; ov.y = av.y + rv.y;
            ov.z = av.z + rv.z; ov.w = av.w + rv.w;
            *(float4*)&obj_s[row][col] = ov;
        }
        __syncthreads();

        // compute: 10 d-quads, 12 ds_read_b128 + 256 VALU each
#pragma unroll 2
        for (int q = 0; q < NQ; ++q) {
            const int col = q * 4;
            float4 e4[8];
#pragma unroll
            for (int j = 0; j < 8; ++j)
                e4[j] = *(const float4*)&ent_s[tx + 16 * j][col];
            float4 o4[4];
#pragma unroll
            for (int i = 0; i < 4; ++i)
                o4[i] = *(const float4*)&obj_s[ty + 16 * i][col];

#pragma unroll
            for (int i = 0; i < 4; ++i) {
#pragma unroll
                for (int j = 0; j < 8; ++j) {
                    // d-ascending chain keeps reference summation order
                    acc[i][j] += fabsf(o4[i].x - e4[j].x);
                    acc[i][j] += fabsf(o4[i].y - e4[j].y);
                    acc[i][j] += fabsf(o4[i].z - e4[j].z);
                    acc[i][j] += fabsf(o4[i].w - e4[j].w);
                }
            }
        }
        __syncthreads();
    }

    // epilogue: sigmoid(GAMMA - dist)
#pragma unroll
    for (int i = 0; i < 4; ++i) {
        const int b_g = bbase + ty + 16 * i;
#pragma unroll
        for (int j = 0; j < 8; ++j) {
            const int n_g = nbase + tx + 16 * j;
            if (n_g < NUM_ENT) {
                const float s = 1.0f / (1.0f + __expf(acc[i][j] - GAMMA));
                out[(size_t)b_g * NUM_ENT + n_g] = s;
            }
        }
    }
}

extern "C" void kernel_launch(void* const* d_in, const int* in_sizes, int n_in,
                              void* d_out, int out_size, void* d_ws, size_t ws_size,
                              hipStream_t stream) {
    const float* ent  = (const float*)d_in[0];
    const float* relE = (const float*)d_in[1];
    const int*   sub  = (const int*)d_in[2];
    const int*   rel  = (const int*)d_in[3];
    float* out = (float*)d_out;

    const int n_tiles = (NUM_ENT + TILE_N - 1) / TILE_N;   // 114
    const int b_tiles = BATCH / TILE_B;                    // 4
    dim3 grid(n_tiles, b_tiles);
    transe_score_kernel<<<grid, 256, 0, stream>>>(ent, relE, sub, rel, out);
}

// Round 4
// 115.363 us; speedup vs baseline: 1.1714x; 1.1714x over previous
//
#include <hip/hip_runtime.h>
#include <hip/hip_fp16.h>
#include <math.h>

#define NUM_ENT 14541
#define NUM_REL2 474
#define EMBED_D 200
#define BATCH 256
#define GAMMA 9.0f

#define TILE 64
#define CHUNK 40                    // halves (d's) per chunk
#define NOCT 5                      // 8-half octs per chunk
#define NCHUNK (EMBED_D / CHUNK)    // 5
#define SLOTS 320                   // NOCT * 64 slots (16 B each) per buffer

#define ENT_OCTS (NUM_ENT * (EMBED_D / 8))   // 363525
#define OBJ_OCTS (BATCH   * (EMBED_D / 8))   // 6400

typedef _Float16 h2 __attribute__((ext_vector_type(2)));

__device__ __forceinline__ void async_ld16(void* lds, const void* g) {
    __builtin_amdgcn_global_load_lds(
        (const __attribute__((address_space(1))) unsigned int*)g,
        (__attribute__((address_space(3))) unsigned int*)lds, 16, 0, 0);
}

__device__ __forceinline__ h2 habs2(h2 x) {
    unsigned u = __builtin_bit_cast(unsigned, x) & 0x7FFF7FFFu;
    return __builtin_bit_cast(h2, u);
}

// acc += sum over 8 dims of |ov - ev| (f16 diffs, fp32 accumulate via v_dot2)
__device__ __forceinline__ float oct_l1(uint4 ov, uint4 ev, float acc, h2 ones) {
    h2 d;
    d = __builtin_bit_cast(h2, ov.x) - __builtin_bit_cast(h2, ev.x);
    acc = __builtin_amdgcn_fdot2(habs2(d), ones, acc, false);
    d = __builtin_bit_cast(h2, ov.y) - __builtin_bit_cast(h2, ev.y);
    acc = __builtin_amdgcn_fdot2(habs2(d), ones, acc, false);
    d = __builtin_bit_cast(h2, ov.z) - __builtin_bit_cast(h2, ev.z);
    acc = __builtin_amdgcn_fdot2(habs2(d), ones, acc, false);
    d = __builtin_bit_cast(h2, ov.w) - __builtin_bit_cast(h2, ev.w);
    acc = __builtin_amdgcn_fdot2(habs2(d), ones, acc, false);
    return acc;
}

// ---------------- prep: fp32 -> fp16 tables ----------------
__global__ __launch_bounds__(256)
void prep_kernel(const float* __restrict__ ent, const float* __restrict__ relE,
                 const int* __restrict__ sub, const int* __restrict__ rel,
                 unsigned int* __restrict__ ent16, unsigned int* __restrict__ obj16)
{
    const int idx = blockIdx.x * 256 + threadIdx.x;
    if (idx < ENT_OCTS) {
        const int e = idx / 25, o = idx - e * 25;
        const float* p = ent + (size_t)e * EMBED_D + o * 8;
        const float4 a = *(const float4*)p;
        const float4 b = *(const float4*)(p + 4);
        uint4 v;
        v.x = __builtin_bit_cast(unsigned, __builtin_amdgcn_cvt_pkrtz(a.x, a.y));
        v.y = __builtin_bit_cast(unsigned, __builtin_amdgcn_cvt_pkrtz(a.z, a.w));
        v.z = __builtin_bit_cast(unsigned, __builtin_amdgcn_cvt_pkrtz(b.x, b.y));
        v.w = __builtin_bit_cast(unsigned, __builtin_amdgcn_cvt_pkrtz(b.z, b.w));
        *(uint4*)(ent16 + (size_t)idx * 4) = v;
    } else if (idx < ENT_OCTS + OBJ_OCTS) {
        const int k = idx - ENT_OCTS;
        const int bI = k / 25, o = k - bI * 25;
        const float* pa = ent  + (size_t)sub[bI] * EMBED_D + o * 8;
        const float* pr = relE + (size_t)rel[bI] * EMBED_D + o * 8;
        const float4 a0 = *(const float4*)pa;
        const float4 a1 = *(const float4*)(pa + 4);
        const float4 r0 = *(const float4*)pr;
        const float4 r1 = *(const float4*)(pr + 4);
        uint4 v;
        v.x = __builtin_bit_cast(unsigned, __builtin_amdgcn_cvt_pkrtz(a0.x + r0.x, a0.y + r0.y));
        v.y = __builtin_bit_cast(unsigned, __builtin_amdgcn_cvt_pkrtz(a0.z + r0.z, a0.w + r0.w));
        v.z = __builtin_bit_cast(unsigned, __builtin_amdgcn_cvt_pkrtz(a1.x + r1.x, a1.y + r1.y));
        v.w = __builtin_bit_cast(unsigned, __builtin_amdgcn_cvt_pkrtz(a1.z + r1.z, a1.w + r1.w));
        *(uint4*)(obj16 + (size_t)k * 4) = v;
    }
}

// ---------------- main: tiled L1-distance + sigmoid ----------------
// 256 threads: tx = tid&15 (n), ty = tid>>4 (b); micro-tile 4x4.
// LDS layout per buffer: slot s = oct*64 + row, 16 B/slot (8 halves).
__global__ __launch_bounds__(256, 4)
void transe_main(const unsigned int* __restrict__ ent16,
                 const unsigned int* __restrict__ obj16,
                 float* __restrict__ out)
{
    __shared__ __align__(16) unsigned int entS[2][SLOTS * 4];
    __shared__ __align__(16) unsigned int objS[2][SLOTS * 4];

    const int tid   = threadIdx.x;
    const int lane  = tid & 63;
    const int wv    = tid >> 6;
    const int nbase = blockIdx.x * TILE;
    const int bbase = blockIdx.y * TILE;

    // staging slots: sA = tid (all 4 waves, slots 0..255);
    // extra slots 256..319: wave0 -> ent, wave1 -> obj
    const int sA = tid;
    const int sX = 256 + lane;
    const int oA = sA >> 6, rA = sA & 63;
    const int oX = sX >> 6, rX = sX & 63;

    int erA = nbase + rA; if (erA >= NUM_ENT) erA = NUM_ENT - 1;
    int erX = nbase + rX; if (erX >= NUM_ENT) erX = NUM_ENT - 1;

    const unsigned int* gEA = ent16 + (size_t)erA * (EMBED_D / 2) + oA * 4;
    const unsigned int* gEX = ent16 + (size_t)erX * (EMBED_D / 2) + oX * 4;
    const unsigned int* gOA = obj16 + (size_t)(bbase + rA) * (EMBED_D / 2) + oA * 4;
    const unsigned int* gOX = obj16 + (size_t)(bbase + rX) * (EMBED_D / 2) + oX * 4;

    const int tx = tid & 15, ty = tid >> 4;
    float acc[4][4] = {};
    h2 ones; ones[0] = (_Float16)1.0f; ones[1] = (_Float16)1.0f;

    // prologue: stage chunk 0 -> buffer 0
    async_ld16(&entS[0][(wv * 64) * 4], gEA);
    async_ld16(&objS[0][(wv * 64) * 4], gOA);
    if (wv == 0)      async_ld16(&entS[0][256 * 4], gEX);
    else if (wv == 1) async_ld16(&objS[0][256 * 4], gOX);
    gEA += CHUNK / 2; gOA += CHUNK / 2; gEX += CHUNK / 2; gOX += CHUNK / 2;
    __syncthreads();

#pragma unroll 1
    for (int c = 0; c < NCHUNK; ++c) {
        const int bb = c & 1;
        if (c + 1 < NCHUNK) {
            const int nb = bb ^ 1;
            async_ld16(&entS[nb][(wv * 64) * 4], gEA);
            async_ld16(&objS[nb][(wv * 64) * 4], gOA);
            if (wv == 0)      async_ld16(&entS[nb][256 * 4], gEX);
            else if (wv == 1) async_ld16(&objS[nb][256 * 4], gOX);
            gEA += CHUNK / 2; gOA += CHUNK / 2; gEX += CHUNK / 2; gOX += CHUNK / 2;
        }

#pragma unroll
        for (int o = 0; o < NOCT; ++o) {
            uint4 ev[4], ov[4];
#pragma unroll
            for (int j = 0; j < 4; ++j)
                ev[j] = *(const uint4*)&entS[bb][(o * 64 + tx + 16 * j) * 4];
#pragma unroll
            for (int i = 0; i < 4; ++i)
                ov[i] = *(const uint4*)&objS[bb][(o * 64 + ty + 16 * i) * 4];
#pragma unroll
            for (int i = 0; i < 4; ++i)
#pragma unroll
                for (int j = 0; j < 4; ++j)
                    acc[i][j] = oct_l1(ov[i], ev[j], acc[i][j], ones);
        }
        __syncthreads();   // drains prefetch vmcnt + protects buffer reuse
    }

    // epilogue: sigmoid(GAMMA - dist)
#pragma unroll
    for (int i = 0; i < 4; ++i) {
        const int b_g = bbase + ty + 16 * i;
#pragma unroll
        for (int j = 0; j < 4; ++j) {
            const int n_g = nbase + tx + 16 * j;
            if (n_g < NUM_ENT) {
                out[(size_t)b_g * NUM_ENT + n_g] =
                    1.0f / (1.0f + __expf(acc[i][j] - GAMMA));
            }
        }
    }
}

extern "C" void kernel_launch(void* const* d_in, const int* in_sizes, int n_in,
                              void* d_out, int out_size, void* d_ws, size_t ws_size,
                              hipStream_t stream) {
    const float* ent  = (const float*)d_in[0];
    const float* relE = (const float*)d_in[1];
    const int*   sub  = (const int*)d_in[2];
    const int*   rel  = (const int*)d_in[3];
    float* out = (float*)d_out;

    unsigned int* ent16 = (unsigned int*)d_ws;
    unsigned int* obj16 = ent16 + (size_t)ENT_OCTS * 4;   // 5,816,400 B offset

    const int prep_total = ENT_OCTS + OBJ_OCTS;
    prep_kernel<<<(prep_total + 255) / 256, 256, 0, stream>>>(ent, relE, sub, rel,
                                                              ent16, obj16);

    dim3 grid((NUM_ENT + TILE - 1) / TILE, BATCH / TILE);   // 228 x 4
    transe_main<<<grid, 256, 0, stream>>>(ent16, obj16, out);
}